// Round 2
// baseline (166.117 us; speedup 1.0000x reference)
//
#include <hip/hip_runtime.h>

// PercolationQ: per-patch occupancy fraction -> threshold -> mean over patches.
// x4:  [3,64,4096, 4, 4]   x8: [3,64,1024, 8, 8]   x16: [3,64, 256,16,16]
// Every input row (c,b) = 65536 floats = 16384 float4; 192 rows per input.
// out: 576 floats = [q4(192) | q8(192) | q16(192)], row-major [c*64+b].
//
// v3: occupancy fix. v1/v2 showed OccupancyPercent ~52-57% — grid quantization
// (2304/4608 blocks vs 2048 co-resident slots) left the machine half-empty in
// the tail while per-wave BW is latency-limited. Now: EXACTLY 2048 equal-work
// blocks (8/CU, one round, zero tail). Work divides perfectly:
//   total float4 = 9,437,184 = 2048 blocks x 18 units x 256 float4
//   units per input = 12288 = 6 x 2048  ->  unit u = b + j*2048, j=0..5,
//   so each block does exactly 6 units of each input (input known at compile time).
// Also: count reduction via __ballot/__popcll (scalar pipe) instead of the
// 6-level shuffle tree; 6 loads in flight per group (24 data VGPRs, <=64 total).

#define PERC_THRESHOLD 0.59275f

template <int B>
__device__ __forceinline__ int patch_count(float4 v, int lane) {
    constexpr int LPP = (B * B) / 4;  // lanes per patch: 4 / 16 / 64
    // wave reads 256 contiguous floats -> patches never straddle a wave chunk
    float s = (v.x + v.y) + (v.z + v.w);
#pragma unroll
    for (int off = 1; off < LPP; off <<= 1)
        s += __shfl_xor(s, off, 64);
    const float thr = PERC_THRESHOLD * (float)(B * B);  // B*B pow2 -> exact
    // one leader lane per patch contributes; ballot+popcount = wave-wide count
    unsigned long long m = __ballot((lane & (LPP - 1)) == 0 && s >= thr);
    return (int)__popcll(m);
}

__global__ __launch_bounds__(256, 8)
void PercolationQ_31885837205970_kernel(const float* __restrict__ x4,
                                        const float* __restrict__ x8,
                                        const float* __restrict__ x16,
                                        float* __restrict__ out) {
    const int tid = threadIdx.x;
    const int lane = tid & 63;
    const int wid = tid >> 6;
    const int b = blockIdx.x;  // 0..2047

    __shared__ int wsum[4][18];  // [wave][unit k]

    const float4* __restrict__ p4 = (const float4*)x4;
    const float4* __restrict__ p8 = (const float4*)x8;
    const float4* __restrict__ p16 = (const float4*)x16;

    float4 v[6];

    // ---- group 0: x4 (B=4), units u = b + j*2048 ----
#pragma unroll
    for (int j = 0; j < 6; ++j)
        v[j] = p4[(long long)(b + j * 2048) * 256 + tid];
#pragma unroll
    for (int j = 0; j < 6; ++j) {
        int c = patch_count<4>(v[j], lane);
        if (lane == 0) wsum[wid][j] = c;
    }

    // ---- group 1: x8 (B=8) ----
#pragma unroll
    for (int j = 0; j < 6; ++j)
        v[j] = p8[(long long)(b + j * 2048) * 256 + tid];
#pragma unroll
    for (int j = 0; j < 6; ++j) {
        int c = patch_count<8>(v[j], lane);
        if (lane == 0) wsum[wid][6 + j] = c;
    }

    // ---- group 2: x16 (B=16) ----
#pragma unroll
    for (int j = 0; j < 6; ++j)
        v[j] = p16[(long long)(b + j * 2048) * 256 + tid];
#pragma unroll
    for (int j = 0; j < 6; ++j) {
        int c = patch_count<16>(v[j], lane);
        if (lane == 0) wsum[wid][12 + j] = c;
    }

    __syncthreads();

    // 18 units -> 18 (input,row) targets. unit u = b + j*2048; row = u>>6
    // (row stride: 16384 float4 = 64 units) -> row = (b>>6) + j*32, exact.
    if (tid < 18) {
        const int input = tid / 6;
        const int j = tid - input * 6;
        float total = (float)(wsum[0][tid] + wsum[1][tid] +
                              wsum[2][tid] + wsum[3][tid]);
        const float invP = (input == 0) ? (1.0f / 4096.0f)
                         : (input == 1) ? (1.0f / 1024.0f)
                                        : (1.0f / 256.0f);  // all 2^-k -> exact
        const int row = (b >> 6) + j * 32;
        atomicAdd(&out[input * 192 + row], total * invP);
    }
}

extern "C" void kernel_launch(void* const* d_in, const int* in_sizes, int n_in,
                              void* d_out, int out_size, void* d_ws, size_t ws_size,
                              hipStream_t stream) {
    const float* x4  = (const float*)d_in[0];
    const float* x8  = (const float*)d_in[1];
    const float* x16 = (const float*)d_in[2];
    float* out = (float*)d_out;

    // d_out is re-poisoned before every launch; we accumulate via atomics.
    hipMemsetAsync(d_out, 0, (size_t)out_size * sizeof(float), stream);

    // exactly 8 blocks/CU x 256 CUs, equal work per block, single round
    dim3 grid(2048), block(256);
    hipLaunchKernelGGL(PercolationQ_31885837205970_kernel, grid, block, 0, stream,
                       x4, x8, x16, out);
}